// Round 4
// baseline (1804.880 us; speedup 1.0000x reference)
//
#include <hip/hip_runtime.h>
#include <cstdint>
#include <cstddef>

typedef _Float16 f16;
typedef _Float16 f16x2 __attribute__((ext_vector_type(2)));
typedef _Float16 f16x8 __attribute__((ext_vector_type(8)));
typedef float f32x4 __attribute__((ext_vector_type(4)));

#define NB_TOT   2048
#define F0_      39
#define DDIM     32
#define HROW     104            // padded hidden row (f16), 208B, 16B-aligned rows
#define HBATCH   (DDIM*HROW)    // 3328 f16 per batch
#define MT_      13             // 13 x 16 = 208 output rows (200 real)
// slab: [step][mt(13)][lane(64)][j(8)] f16  -> per-step 6656 f16 = 13312 B = 832 x 16B
#define SLAB_F16S 6656
#define SLAB_BYTES 13312

// workspace layout (bytes)
#define SZ_H     ((size_t)NB_TOT*HBATCH*2)
#define OFF_H0   ((size_t)0)
#define OFF_H1   (OFF_H0 + SZ_H)
#define OFF_H2   (OFF_H1 + SZ_H)
#define OFF_W0   (OFF_H2 + SZ_H)
#define SZ_W0    ((size_t)50*SLAB_BYTES)
#define OFF_W1   (OFF_W0 + SZ_W0)
#define SZ_W12   ((size_t)130*SLAB_BYTES)
#define OFF_W2   (OFF_W1 + SZ_W12)
#define OFF_BIAS (OFF_W2 + SZ_W12)

// ---------------- prep kernels ----------------

// h0[b][d][n] = (n<39) ? x[b][n][d] : 0   (fp16, transposed, zero-padded)
__global__ void k_prep_h0(const float* __restrict__ x, f16* __restrict__ h0) {
    long idx = (long)blockIdx.x * 256 + threadIdx.x;
    if (idx >= (long)NB_TOT * HBATCH) return;
    int n = (int)(idx % HROW);
    long t = idx / HROW;
    int d = (int)(t % DDIM);
    long b = t / DDIM;
    float v = 0.f;
    if (n < F0_) v = x[(b * F0_ + n) * DDIM + d];
    h0[idx] = (f16)v;
}

// slab[step][mt][lane][j] = W[m*hn+n][o]
//   lane = quad*16+d0; o = mt*16+d0; m = (step%10)*4+quad; n = (step/10)*8+j
// zeros where o>=200 | m>=39 | n>=hn  (m padded to 40, n padded to runs*8)
__global__ void k_prep_w(const float* __restrict__ W, f16* __restrict__ slab,
                         int nsteps, int hn) {
    long idx = (long)blockIdx.x * 256 + threadIdx.x;
    if (idx >= (long)nsteps * SLAB_F16S) return;
    int j = (int)(idx & 7);
    long t = idx >> 3;
    int lane = (int)(t & 63); t >>= 6;
    int mt = (int)(t % 13);
    int step = (int)(t / 13);
    int quad = lane >> 4, d0 = lane & 15;
    int o = mt * 16 + d0;
    int m = (step % 10) * 4 + quad;
    int n = (step / 10) * 8 + j;
    float v = 0.f;
    if (o < 200 && m < F0_ && n < hn)
        v = W[((long)m * hn + n) * 200 + o];
    slab[idx] = (f16)v;
}

__global__ void k_prep_bias(const float* __restrict__ b0, const float* __restrict__ b1,
                            const float* __restrict__ b2, float* __restrict__ dst) {
    int idx = blockIdx.x * 256 + threadIdx.x;
    if (idx >= 3 * 208) return;
    int L = idx / 208, o = idx % 208;
    const float* s = (L == 0) ? b0 : (L == 1 ? b1 : b2);
    dst[idx] = (o < 200) ? s[o] : 0.f;
}

// ---------------- main layer kernel ----------------

__device__ __forceinline__ void gl_lds16(const void* g, void* l) {
    __builtin_amdgcn_global_load_lds(
        (const __attribute__((address_space(1))) unsigned int*)g,
        (__attribute__((address_space(3))) unsigned int*)l,
        16, 0, 0);
}

// stage one step-slab (832 x 16B chunks) with 256 threads: 3 full rounds + 64 tail
__device__ __forceinline__ void stage_slab(const f16* __restrict__ g, f16* l, int tid) {
#pragma unroll
    for (int rr = 0; rr < 3; ++rr) {
        int c = rr * 256 + tid;
        gl_lds16((const char*)g + (size_t)c * 16, (char*)l + (size_t)c * 16);
    }
    if (tid < 64) {
        int c = 768 + tid;
        gl_lds16((const char*)g + (size_t)c * 16, (char*)l + (size_t)c * 16);
    }
}

// 4 waves/block, 4 batches/block. Wave (half,pair): half = M-split (mt 0-6 / 7-12),
// pair = batch pair. K-order: nrun-major; x register-resident; h register-resident per nrun.
template <int NR>
__global__ __launch_bounds__(256, 2) void k_layer(
    const f16* __restrict__ xg,     // transposed x (= h0 buffer), [2048][32][104]
    const f16* __restrict__ hg,     // hidden input, same layout
    const f16* __restrict__ slabg,  // [NR*10][6656] f16, permuted layout
    const float* __restrict__ biasg,// [208], zero-padded
    f16* __restrict__ houtg,        // next hidden (or nullptr)
    float* __restrict__ outg,       // d_out [2048][400]
    int direct_lo, int outbase) {
    constexpr int NSTEPS = NR * 10;
    __shared__ __align__(16) f16 slab_lds[2][SLAB_F16S];   // 26624 B ring-2
    __shared__ __align__(16) f16 hl[4][HBATCH];            // 26624 B

    const int tid = threadIdx.x;
    const int w = tid >> 6;
    const int lane = tid & 63;
    const int pair = w & 1;          // which batch pair
    const int half = w >> 1;         // which M half
    const int b0i = blockIdx.x * 4 + pair * 2;
    const int quad = lane >> 4;
    const int d0 = lane & 15;
    const int mtbase = half * 7;     // 0 or 7
    const int nmt = half ? 6 : 7;    // 7 + 6 = 13 tiles

    // stage hidden: wave w copies batch w of this block (coalesced u32 copy)
    {
        const unsigned int* src = (const unsigned int*)(hg + (size_t)(blockIdx.x * 4 + w) * HBATCH);
        unsigned int* dst = (unsigned int*)&hl[w][0];
        for (int i = lane; i < HBATCH / 2; i += 64) dst[i] = src[i];
    }
    stage_slab(slabg, &slab_lds[0][0], tid);

    // preload ALL x scalars this lane ever needs: xr[b][mg] = {d-half0, d-half1}
    const f16* xrow0 = xg + (size_t)(b0i + 0) * HBATCH;
    const f16* xrow1 = xg + (size_t)(b0i + 1) * HBATCH;
    f16x2 xr0[10], xr1[10];          // 20 VGPRs
#pragma unroll
    for (int mg = 0; mg < 10; ++mg) {
        int m = mg * 4 + quad;       // m=39 is the zero pad row
        xr0[mg][0] = xrow0[d0 * HROW + m];
        xr0[mg][1] = xrow0[(d0 + 16) * HROW + m];
        xr1[mg][0] = xrow1[d0 * HROW + m];
        xr1[mg][1] = xrow1[(d0 + 16) * HROW + m];
    }

    f32x4 acc[7][2][2];              // [mt][d-half][batch] = 112 VGPRs
#pragma unroll
    for (int mt = 0; mt < 7; ++mt)
#pragma unroll
        for (int nt = 0; nt < 2; ++nt)
#pragma unroll
            for (int bb = 0; bb < 2; ++bb)
                acc[mt][nt][bb] = (f32x4)0.f;

    const f16* hl0 = &hl[pair * 2 + 0][0];
    const f16* hl1 = &hl[pair * 2 + 1][0];

    __syncthreads();   // prologue: hl staged + slab(0) landed (full drain, once)

    for (int nr = 0; nr < NR; ++nr) {
        // h fragments for this nrun: h[d][nr*8 .. nr*8+7], register-resident 10 steps
        f16x8 h00 = *(const f16x8*)&hl0[d0 * HROW + nr * 8];
        f16x8 h01 = *(const f16x8*)&hl0[(d0 + 16) * HROW + nr * 8];
        f16x8 h10 = *(const f16x8*)&hl1[d0 * HROW + nr * 8];
        f16x8 h11 = *(const f16x8*)&hl1[(d0 + 16) * HROW + nr * 8];

#pragma unroll
        for (int mg = 0; mg < 10; ++mg) {
            const int s = nr * 10 + mg;
            // slab(s) guaranteed landed after this wait+barrier (issued 1 step ago)
            asm volatile("s_waitcnt vmcnt(0)" ::: "memory");
            __builtin_amdgcn_s_barrier();
            if (s + 1 < NSTEPS)
                stage_slab(slabg + (size_t)(s + 1) * SLAB_F16S,
                           &slab_lds[(mg + 1) & 1][0], tid);

            // B fragments: Z[k][d] = x[d,m]*h[d,n];  k = quad*8+j -> (m=mg*4+quad, n=nr*8+j)
            f16x8 b00 = h00 * xr0[mg][0];
            f16x8 b01 = h01 * xr0[mg][1];
            f16x8 b10 = h10 * xr1[mg][0];
            f16x8 b11 = h11 * xr1[mg][1];

            const f16* abase = &slab_lds[mg & 1][lane * 8];   // +mt*512: linear, 0-conflict
            __builtin_amdgcn_s_setprio(1);
#pragma unroll
            for (int mt = 0; mt < 7; ++mt) {
                if (mt < nmt) {
                    f16x8 a = *(const f16x8*)(abase + (mtbase + mt) * 512);
                    acc[mt][0][0] = __builtin_amdgcn_mfma_f32_16x16x32_f16(a, b00, acc[mt][0][0], 0, 0, 0);
                    acc[mt][1][0] = __builtin_amdgcn_mfma_f32_16x16x32_f16(a, b01, acc[mt][1][0], 0, 0, 0);
                    acc[mt][0][1] = __builtin_amdgcn_mfma_f32_16x16x32_f16(a, b10, acc[mt][0][1], 0, 0, 0);
                    acc[mt][1][1] = __builtin_amdgcn_mfma_f32_16x16x32_f16(a, b11, acc[mt][1][1], 0, 0, 0);
                }
            }
            __builtin_amdgcn_s_setprio(0);
        }
    }

    // -------- epilogue --------
    asm volatile("s_waitcnt vmcnt(0)" ::: "memory");  // drain any in-flight LDS writes
    __syncthreads();

    const bool wrh = (houtg != nullptr);
    f16* scratch0 = ((f16*)slab_lds) + (pair * 2 + 0) * HBATCH;  // 4*6656B == 26624B: exact fit
    f16* scratch1 = ((f16*)slab_lds) + (pair * 2 + 1) * HBATCH;
    if (wrh && half == 0) {    // one wave per batch-pair zeroes both scratches
        unsigned int* sz0 = (unsigned int*)scratch0;
        unsigned int* sz1 = (unsigned int*)scratch1;
        for (int i = lane; i < HBATCH / 2; i += 64) { sz0[i] = 0u; sz1[i] = 0u; }
    }
    __syncthreads();

#pragma unroll
    for (int mt = 0; mt < 7; ++mt) {
        if (mt < nmt) {
#pragma unroll
            for (int bb = 0; bb < 2; ++bb) {
                f16* scratch = bb ? scratch1 : scratch0;
                float v[2][4];
#pragma unroll
                for (int nt = 0; nt < 2; ++nt)
#pragma unroll
                    for (int i = 0; i < 4; ++i) {
                        int o = (mtbase + mt) * 16 + quad * 4 + i;
                        float t = acc[mt][nt][bb][i] + biasg[o];
                        v[nt][i] = t > 0.f ? t : 0.f;
                    }
                if (wrh && half == 0) {  // hidden rows o<100 all live in half 0
#pragma unroll
                    for (int nt = 0; nt < 2; ++nt)
#pragma unroll
                        for (int i = 0; i < 4; ++i) {
                            int o = mt * 16 + quad * 4 + i;
                            if (o < 100) scratch[(d0 + 16 * nt) * HROW + o] = (f16)v[nt][i];
                        }
                }
                float s[4];
#pragma unroll
                for (int i = 0; i < 4; ++i) s[i] = v[0][i] + v[1][i];
#pragma unroll
                for (int mask = 1; mask <= 8; mask <<= 1)
#pragma unroll
                    for (int i = 0; i < 4; ++i) s[i] += __shfl_xor(s[i], mask, 64);
                if (d0 == 0) {
#pragma unroll
                    for (int i = 0; i < 4; ++i) {
                        int o = (mtbase + mt) * 16 + quad * 4 + i;
                        if (o >= direct_lo && o < 200)
                            outg[(size_t)(b0i + bb) * 400 + outbase + (o - direct_lo)] = s[i];
                    }
                }
            }
        }
    }

    if (wrh) {
        __syncthreads();
        // wave w copies scratch of batch w back to global
        const unsigned int* s2 = (const unsigned int*)(((f16*)slab_lds) + w * HBATCH);
        unsigned int* dg = (unsigned int*)(houtg + (size_t)(blockIdx.x * 4 + w) * HBATCH);
        for (int i = lane; i < HBATCH / 2; i += 64) dg[i] = s2[i];
    }
}

// ---------------- launch ----------------

extern "C" void kernel_launch(void* const* d_in, const int* in_sizes, int n_in,
                              void* d_out, int out_size, void* d_ws, size_t ws_size,
                              hipStream_t stream) {
    const float* x  = (const float*)d_in[0];
    const float* W0 = (const float*)d_in[1];
    const float* b0 = (const float*)d_in[2];
    const float* W1 = (const float*)d_in[3];
    const float* b1 = (const float*)d_in[4];
    const float* W2 = (const float*)d_in[5];
    const float* b2 = (const float*)d_in[6];
    float* out = (float*)d_out;
    char* ws = (char*)d_ws;

    f16* h0 = (f16*)(ws + OFF_H0);
    f16* h1 = (f16*)(ws + OFF_H1);
    f16* h2 = (f16*)(ws + OFF_H2);
    f16* w0s = (f16*)(ws + OFF_W0);
    f16* w1s = (f16*)(ws + OFF_W1);
    f16* w2s = (f16*)(ws + OFF_W2);
    float* biasws = (float*)(ws + OFF_BIAS);

    {
        long tot = (long)NB_TOT * HBATCH;
        k_prep_h0<<<(unsigned)((tot + 255) / 256), 256, 0, stream>>>(x, h0);
    }
    k_prep_w<<<(unsigned)(((long)50 * SLAB_F16S + 255) / 256), 256, 0, stream>>>(W0, w0s, 50, 39);
    k_prep_w<<<(unsigned)(((long)130 * SLAB_F16S + 255) / 256), 256, 0, stream>>>(W1, w1s, 130, 100);
    k_prep_w<<<(unsigned)(((long)130 * SLAB_F16S + 255) / 256), 256, 0, stream>>>(W2, w2s, 130, 100);
    k_prep_bias<<<3, 256, 0, stream>>>(b0, b1, b2, biasws);

    // layer 0: hidden=x (hn=39, NR=5); direct = cur[100:200] -> out[:,0:100)
    k_layer<5><<<512, 256, 0, stream>>>(h0, h0, w0s, biasws + 0, h1, out, 100, 0);
    // layer 1: hn=100, NR=13; direct = cur[100:200] -> out[:,100:200)
    k_layer<13><<<512, 256, 0, stream>>>(h0, h1, w1s, biasws + 208, h2, out, 100, 100);
    // layer 2: hn=100, NR=13; direct = full cur -> out[:,200:400)
    k_layer<13><<<512, 256, 0, stream>>>(h0, h2, w2s, biasws + 416, (f16*)nullptr, out, 0, 200);
}